// Round 16
// baseline (717.548 us; speedup 1.0000x reference)
//
#include <hip/hip_runtime.h>
#include <hip/hip_fp16.h>

#define NN 100   // nodes
#define HH 32    // hidden
#define BB 8192  // batch
#define DD 32    // dags
#define KP 128   // padded K
#define TPB 1024 // 16 waves per block, 32 rows per wave, 512 rows per block

typedef _Float16 f16x8 __attribute__((ext_vector_type(8)));
typedef __fp16 fph2 __attribute__((ext_vector_type(2)));
typedef _Float16 f16x2 __attribute__((ext_vector_type(2)));
typedef float f32x4 __attribute__((ext_vector_type(4)));
typedef unsigned short ushort_t;
typedef unsigned int uint_t;
union FU { uint4 u; f16x8 h; };
union PU { fph2 p; f16x2 h; uint_t u; };

#define AS_GLOBAL __attribute__((address_space(1)))
#define AS_LDS    __attribute__((address_space(3)))

#define SELQ(arr, qq) ((qq) == 0 ? arr[0] : (qq) == 1 ? arr[1] : (qq) == 2 ? arr[2] : arr[3])

// LDS: stage 2 sets x 4 tiles x 8192B = 65536 @0; epi4 6400 @65536; b2t 400 @71936
#define EPI4_OFF 65536
#define B2T_OFF 71936
#define SMEM_BYTES 72336

// ======================= prep =======================
// x (B,N) f32 -> xTh (N,B) fp16 (plain transpose)
__global__ void prep_xth(const float* __restrict__ x, ushort_t* __restrict__ xTh) {
  int idx = blockIdx.x * 256 + threadIdx.x;
  if (idx >= BB * NN) return;
  int b = idx & (BB - 1);
  int n = idx >> 13;
  xTh[idx] = __half_as_ushort(__float2half_rn(x[(size_t)b * NN + n]));
}

// W1M[d][node]: 32x128 fp16 tile, swizzled (j*128+k)^((j&7)<<3)
// k<100: mask*W1; k==100: x-weight; k==101: b1; else 0
__global__ void prep_w1m(const float* __restrict__ A, const float* __restrict__ W1,
                         const float* __restrict__ b1, ushort_t* __restrict__ W1M) {
  int idx = blockIdx.x * 256 + threadIdx.x;   // DD*NN*4096
  int tile = idx >> 12;
  int d = tile / NN;
  int node = tile - d * NN;
  int rem = idx & 4095;
  int j = rem >> 7;
  int k = rem & 127;
  float v = 0.f;
  if (k < NN) {
    float m = A[((size_t)d * NN + k) * NN + node];
    v = (m != 0.f) ? W1[((size_t)node * HH + j) * (NN + 1) + k] : 0.f;
  } else if (k == NN) {
    v = W1[((size_t)node * HH + j) * (NN + 1) + NN];
  } else if (k == NN + 1) {
    v = b1[node * HH + j];
  }
  int t = (j * KP + k) ^ ((j & 7) << 3);
  W1M[(size_t)tile * 4096 + t] = __half_as_ushort(__float2half_rn(v));
}

// epi4[node][16 uints]: per g slot, B-frag-order W2 pairs:
// x=(W2[4g],W2[4g+1]) y=(4g+2,4g+3) z=(16+4g,16+4g+1) w=(16+4g+2,16+4g+3); b2t
__global__ void prep_epi4(const float* __restrict__ W2, const float* __restrict__ b2,
                          uint_t* __restrict__ epi4, float* __restrict__ b2t) {
  int idx = blockIdx.x * 256 + threadIdx.x;
  if (idx < NN * 16) {
    int node = idx >> 4;
    int g = (idx >> 2) & 3;
    int r = idx & 3;
    int j0 = ((r & 2) << 3) + 4 * g + ((r & 1) << 1);
    uint_t lo = __half_as_ushort(__float2half_rn(W2[node * HH + j0]));
    uint_t hi = __half_as_ushort(__float2half_rn(W2[node * HH + j0 + 1]));
    epi4[idx] = lo | (hi << 16);
  } else if (idx < NN * 16 + NN) {
    int node = idx - NN * 16;
    b2t[node] = b2[node];
  }
}

// ======================= main =======================
__global__ __launch_bounds__(TPB, 8) void dag_mfma_em(
    const ushort_t* __restrict__ xTh,  // [N][B] fp16
    const int* __restrict__ order,     // [D][N]
    const int* __restrict__ do_idx_p,  // [1]
    const ushort_t* __restrict__ W1M,  // [D][N][4096] fp16 swizzled
    const uint_t* __restrict__ epi4_g, // [N][16]
    const float* __restrict__ b2t_g,   // [N]
    float* __restrict__ out)           // [D][B][N]
{
  __shared__ __align__(16) char smem[SMEM_BYTES];
  const char* sp = (const char*)smem;

  const int d = blockIdx.y;
  const int bx = blockIdx.x;
  const int tid = threadIdx.x;
  const int w = tid >> 6;        // 16 waves
  const int lane = tid & 63;
  const int g = lane >> 4;
  const int n16 = lane & 15;
  const int di = __builtin_amdgcn_readfirstlane(do_idx_p[0]);
  const int* ord = order + d * NN;
  const int rowbase = bx * 512 + w * 32 + n16;

  // preloads: epi4 (400 uint4), b2t (100 f32)
  {
    const uint4* s4 = (const uint4*)epi4_g;
    uint4* d4 = (uint4*)(smem + EPI4_OFF);
    for (int i = tid; i < 400; i += TPB) d4[i] = s4[i];
    if (tid < NN) ((float*)(smem + B2T_OFF))[tid] = b2t_g[tid];
  }

  const ushort_t* Wd = W1M + (size_t)d * NN * 4096;

  // per-lane swizzled within-tile byte offsets, per S
  int vs[4];
#pragma unroll
  for (int S = 0; S < 4; ++S) {
    int hw = n16 * KP + ((8 * g) ^ ((n16 & 3) << 3)) + 32 * (S ^ ((n16 >> 2) & 1));
    vs[S] = 2 * hw;
  }
  int tsb = 32768;   // toggled to 0 at first superstep top

  // nodes for superstep 0; prologue DMA into set 0
  int nd[4], nn2[4];
#pragma unroll
  for (int q = 0; q < 4; ++q) { nd[q] = __builtin_amdgcn_readfirstlane(ord[q]); nn2[q] = nd[q]; }
  {
    const int q2 = tid >> 8, sub = tid & 255;   // 256 threads per tile
    const int nsel = SELQ(nd, q2);
    const char* gb = (const char*)(Wd + (size_t)nsel * 4096);
    char* lb = (char*)smem + q2 * 8192;
    __builtin_amdgcn_global_load_lds((const AS_GLOBAL void*)(gb + sub * 16),
                                     (AS_LDS void*)(lb + sub * 16), 16, 0, 0);
    __builtin_amdgcn_global_load_lds((const AS_GLOBAL void*)(gb + 4096 + sub * 16),
                                     (AS_LDS void*)(lb + 4096 + sub * 16), 16, 0, 0);
  }
  // x for step 0 (global, fp16 bits)
  ushort_t xbc[2], xbn[2];
  {
    const ushort_t* xp = xTh + (size_t)nd[0] * BB + rowbase;
    xbc[0] = xp[0];
    xbc[1] = xp[16];
  }

  // breg[nt][S]: lane(g,n16) holds k=32S+8g+{0..7}, row rowbase+16nt
  // k=101 (S=3 .z hi, g==0) = 1.0 (b1 row); k=100 (.z lo) = per-step x
  uint4 breg[2][4];
#pragma unroll
  for (int nt = 0; nt < 2; ++nt) {
#pragma unroll
    for (int S = 0; S < 4; ++S) breg[nt][S] = make_uint4(0u, 0u, 0u, 0u);
    breg[nt][3].z = (g == 0) ? 0x3C000000u : 0u;
  }

  const f32x4 zero4 = {0.f, 0.f, 0.f, 0.f};
  PU c001; c001.u = 0x211F211Fu;   // fp16 0.01 x2

#pragma unroll 1
  for (int ss = 0; ss < 25; ++ss) {
    asm volatile("s_waitcnt vmcnt(0) lgkmcnt(0)" ::: "memory");
    __builtin_amdgcn_s_barrier();
    __builtin_amdgcn_sched_barrier(0);

    tsb ^= 32768;

    if (ss < 24) {
#pragma unroll
      for (int q = 0; q < 4; ++q)
        nn2[q] = __builtin_amdgcn_readfirstlane(ord[4 * (ss + 1) + q]);
      const int dset = tsb ^ 32768;
      const int q2 = tid >> 8, sub = tid & 255;
      const int nsel = SELQ(nn2, q2);
      const char* gb = (const char*)(Wd + (size_t)nsel * 4096);
      char* lb = (char*)smem + dset + q2 * 8192;
      __builtin_amdgcn_global_load_lds((const AS_GLOBAL void*)(gb + sub * 16),
                                       (AS_LDS void*)(lb + sub * 16), 16, 0, 0);
      __builtin_amdgcn_global_load_lds((const AS_GLOBAL void*)(gb + 4096 + sub * 16),
                                       (AS_LDS void*)(lb + 4096 + sub * 16), 16, 0, 0);
    }

    // ---- 4 steps, barrier-free
#pragma unroll
    for (int q = 0; q < 4; ++q) {
      const int node = nd[q];

      // prefetch next step's x
      {
        const int node_nx = (q < 3) ? nd[q + 1] : nn2[0];
        const ushort_t* xp = xTh + (size_t)node_nx * BB + rowbase;
        xbn[0] = xp[0];
        xbn[1] = xp[16];
      }

      // insert x at k=100 (S=3 .z lo, owner g==0); hi half is 1.0
#pragma unroll
      for (int nt = 0; nt < 2; ++nt) {
        uint_t ins = 0x3C000000u | (uint_t)xbc[nt];
        breg[nt][3].z = (g == 0) ? ins : breg[nt][3].z;
      }

      // insert coordinates for k=node (wave-uniform)
      const int sn = node >> 5;
      const int en2 = (node >> 1) & 3;
      const int gn = (node >> 3) & 3;
      const int hin = node & 1;
      const bool own = (g == gn);

      ushort_t hv[2];
      if (node != di) {
        const uint4 w4 = *(const uint4*)(sp + EPI4_OFF + node * 64 + g * 16);
        const float b2n = *(const float*)(sp + B2T_OFF + node * 4);
        const int tb = tsb + q * 8192;

        f32x4 acc0[2], acc1[2];

        __builtin_amdgcn_s_setprio(1);
#pragma unroll
        for (int S = 0; S < 4; ++S) {
          FU a0, a1;
          a0.u = *(const uint4*)(sp + tb + vs[S]);
          a1.u = *(const uint4*)(sp + tb + 4096 + vs[S]);
#pragma unroll
          for (int nt = 0; nt < 2; ++nt) {
            FU bu; bu.u = breg[nt][S];
            if (S == 0) {
              acc0[nt] = __builtin_amdgcn_mfma_f32_16x16x32_f16(a0.h, bu.h, zero4, 0, 0, 0);
              acc1[nt] = __builtin_amdgcn_mfma_f32_16x16x32_f16(a1.h, bu.h, zero4, 0, 0, 0);
            } else {
              acc0[nt] = __builtin_amdgcn_mfma_f32_16x16x32_f16(a0.h, bu.h, acc0[nt], 0, 0, 0);
              acc1[nt] = __builtin_amdgcn_mfma_f32_16x16x32_f16(a1.h, bu.h, acc1[nt], 0, 0, 0);
            }
          }
        }
        __builtin_amdgcn_s_setprio(0);

        // epilogue MFMA: A = W2 (B-frag order) on single row i0=4*gn; C = b2 splat
        const int i0 = 4 * gn;
        const bool arow = (n16 == i0);
        uint4 aepi;
        aepi.x = arow ? w4.x : 0u;
        aepi.y = arow ? w4.y : 0u;
        aepi.z = arow ? w4.z : 0u;
        aepi.w = arow ? w4.w : 0u;
        const f32x4 cb2 = {b2n, b2n, b2n, b2n};

#pragma unroll
        for (int nt = 0; nt < 2; ++nt) {
          PU h01, h23, h45, h67;
          h01.p = __builtin_amdgcn_cvt_pkrtz(acc0[nt][0], acc0[nt][1]);
          h23.p = __builtin_amdgcn_cvt_pkrtz(acc0[nt][2], acc0[nt][3]);
          h45.p = __builtin_amdgcn_cvt_pkrtz(acc1[nt][0], acc1[nt][1]);
          h67.p = __builtin_amdgcn_cvt_pkrtz(acc1[nt][2], acc1[nt][3]);
          h01.p = __builtin_elementwise_max(h01.p, h01.p * c001.p);
          h23.p = __builtin_elementwise_max(h23.p, h23.p * c001.p);
          h45.p = __builtin_elementwise_max(h45.p, h45.p * c001.p);
          h67.p = __builtin_elementwise_max(h67.p, h67.p * c001.p);
          FU bm;
          bm.u = make_uint4(h01.u, h23.u, h45.u, h67.u);
          f32x4 dv = __builtin_amdgcn_mfma_f32_16x16x32_f16(
              ((FU*)&aepi)->h, bm.h, cb2, 0, 0, 0);
          // val (dot + b2) lands in dv[0] on lanes g==gn, col = n16
          hv[nt] = __half_as_ushort(__float2half_rn(dv[0]));
        }
      } else {
        hv[0] = xbc[0];
        hv[1] = xbc[1];
      }

      // insert hv at k=node: wave-uniform selects
#pragma unroll
      for (int S = 0; S < 4; ++S) {
        if (S != sn) continue;    // uniform
#pragma unroll
        for (int nt = 0; nt < 2; ++nt) {
          uint4& Bq = breg[nt][S];
          uint_t hvn = (uint_t)hv[nt];
          if (en2 == 0) {
            uint_t old = Bq.x;
            uint_t nw = hin ? ((old & 0x0000FFFFu) | (hvn << 16)) : ((old & 0xFFFF0000u) | hvn);
            Bq.x = own ? nw : old;
          } else if (en2 == 1) {
            uint_t old = Bq.y;
            uint_t nw = hin ? ((old & 0x0000FFFFu) | (hvn << 16)) : ((old & 0xFFFF0000u) | hvn);
            Bq.y = own ? nw : old;
          } else if (en2 == 2) {
            uint_t old = Bq.z;
            uint_t nw = hin ? ((old & 0x0000FFFFu) | (hvn << 16)) : ((old & 0xFFFF0000u) | hvn);
            Bq.z = own ? nw : old;
          } else {
            uint_t old = Bq.w;
            uint_t nw = hin ? ((old & 0x0000FFFFu) | (hvn << 16)) : ((old & 0xFFFF0000u) | hvn);
            Bq.w = own ? nw : old;
          }
        }
      }

      xbc[0] = xbn[0];
      xbc[1] = xbn[1];
    }

#pragma unroll
    for (int q = 0; q < 4; ++q) nd[q] = nn2[q];
  }

  // ---- output: per-wave 32-row LDS transpose chunks
  ushort_t* tbuf = (ushort_t*)smem;   // 32*132 halfs = 8448B (stage area reuse)
#pragma unroll 1
  for (int c = 0; c < 16; ++c) {
    __syncthreads();
    if (w == c) {
#pragma unroll
      for (int nt = 0; nt < 2; ++nt) {
        int r = nt * 16 + n16;
#pragma unroll
        for (int S = 0; S < 4; ++S) {
          int k = 32 * S + 8 * g;
          *(uint2*)&tbuf[r * 132 + k] = make_uint2(breg[nt][S].x, breg[nt][S].y);
          *(uint2*)&tbuf[r * 132 + k + 4] = make_uint2(breg[nt][S].z, breg[nt][S].w);
        }
      }
    }
    __syncthreads();
    const size_t obase = ((size_t)d * BB + bx * 512 + c * 32) * NN;
    for (int idx = tid; idx < 32 * NN; idx += TPB) {
      int rl = idx / NN;
      int col = idx - rl * NN;
      out[obase + idx] = __half2float(__ushort_as_half(tbuf[rl * 132 + col]));
    }
  }
}

// ======================= launch =======================
extern "C" void kernel_launch(void* const* d_in, const int* in_sizes, int n_in,
                              void* d_out, int out_size, void* d_ws, size_t ws_size,
                              hipStream_t stream) {
  const float* x     = (const float*)d_in[0];
  const float* A     = (const float*)d_in[1];
  const int* order   = (const int*)d_in[2];
  const int* do_idx  = (const int*)d_in[3];
  const float* W1    = (const float*)d_in[4];
  const float* b1    = (const float*)d_in[5];
  const float* W2    = (const float*)d_in[6];
  const float* b2    = (const float*)d_in[7];
  float* out = (float*)d_out;

  char* ws = (char*)d_ws;
  const size_t XTH_B = (size_t)BB * NN * 2;         // 1,638,400
  const size_t W1M_B = (size_t)DD * NN * 4096 * 2;  // 26,214,400
  ushort_t* xTh = (ushort_t*)ws;
  ushort_t* W1M = (ushort_t*)(ws + XTH_B);
  uint_t* epi4  = (uint_t*)(ws + XTH_B + W1M_B);            // 6,400 B
  float* b2t    = (float*)(ws + XTH_B + W1M_B + 6400);      // 400 B

  hipLaunchKernelGGL(prep_xth, dim3((BB * NN) / 256), dim3(256), 0, stream, x, xTh);
  hipLaunchKernelGGL(prep_w1m, dim3((DD * NN * 4096) / 256), dim3(256), 0, stream,
                     A, W1, b1, W1M);
  hipLaunchKernelGGL(prep_epi4, dim3((NN * 16 + NN + 255) / 256), dim3(256), 0, stream,
                     W2, b2, epi4, b2t);
  hipLaunchKernelGGL(dag_mfma_em, dim3(BB / 512, DD), dim3(TPB), 0, stream,
                     xTh, order, do_idx, W1M, epi4, b2t, out);
}

// Round 17
// 285.152 us; speedup vs baseline: 2.5164x; 2.5164x over previous
//
#include <hip/hip_runtime.h>
#include <hip/hip_fp16.h>

#define NN 100   // nodes
#define HH 32    // hidden
#define BB 8192  // batch
#define DD 32    // dags
#define KP 128   // padded K
#define TPB 1024 // 16 waves per block, 32 rows per wave, 512 rows per block

typedef _Float16 f16x8 __attribute__((ext_vector_type(8)));
typedef __fp16 fph2 __attribute__((ext_vector_type(2)));
typedef _Float16 f16x2 __attribute__((ext_vector_type(2)));
typedef float f32x4 __attribute__((ext_vector_type(4)));
typedef unsigned short ushort_t;
typedef unsigned int uint_t;
union FU { uint4 u; f16x8 h; };
union PU { fph2 p; f16x2 h; uint_t u; };

#define AS_GLOBAL __attribute__((address_space(1)))
#define AS_LDS    __attribute__((address_space(3)))

#define SELQ(arr, qq) ((qq) == 0 ? arr[0] : (qq) == 1 ? arr[1] : (qq) == 2 ? arr[2] : arr[3])

// LDS: stage 2 sets x 4 tiles x 8192B = 65536 @0; epi4 6400 @65536; b2t 400 @71936
#define EPI4_OFF 65536
#define B2T_OFF 71936
#define SMEM_BYTES 72336

// ======================= prep =======================
// x (B,N) f32 -> xTh (N,B) fp16 (plain transpose)
__global__ void prep_xth(const float* __restrict__ x, ushort_t* __restrict__ xTh) {
  int idx = blockIdx.x * 256 + threadIdx.x;
  if (idx >= BB * NN) return;
  int b = idx & (BB - 1);
  int n = idx >> 13;
  xTh[idx] = __half_as_ushort(__float2half_rn(x[(size_t)b * NN + n]));
}

// W1M[d][node]: 32x128 fp16 tile, swizzled (j*128+k)^((j&7)<<3)
// k<100: mask*W1; k==100: x-weight; k==101: b1; else 0
__global__ void prep_w1m(const float* __restrict__ A, const float* __restrict__ W1,
                         const float* __restrict__ b1, ushort_t* __restrict__ W1M) {
  int idx = blockIdx.x * 256 + threadIdx.x;   // DD*NN*4096
  int tile = idx >> 12;
  int d = tile / NN;
  int node = tile - d * NN;
  int rem = idx & 4095;
  int j = rem >> 7;
  int k = rem & 127;
  float v = 0.f;
  if (k < NN) {
    float m = A[((size_t)d * NN + k) * NN + node];
    v = (m != 0.f) ? W1[((size_t)node * HH + j) * (NN + 1) + k] : 0.f;
  } else if (k == NN) {
    v = W1[((size_t)node * HH + j) * (NN + 1) + NN];
  } else if (k == NN + 1) {
    v = b1[node * HH + j];
  }
  int t = (j * KP + k) ^ ((j & 7) << 3);
  W1M[(size_t)tile * 4096 + t] = __half_as_ushort(__float2half_rn(v));
}

// epi4[node][16 uints]: per g slot, B-frag-order W2 pairs:
// x=(W2[4g],W2[4g+1]) y=(4g+2,4g+3) z=(16+4g,16+4g+1) w=(16+4g+2,16+4g+3); b2t
__global__ void prep_epi4(const float* __restrict__ W2, const float* __restrict__ b2,
                          uint_t* __restrict__ epi4, float* __restrict__ b2t) {
  int idx = blockIdx.x * 256 + threadIdx.x;
  if (idx < NN * 16) {
    int node = idx >> 4;
    int g = (idx >> 2) & 3;
    int r = idx & 3;
    int j0 = ((r & 2) << 3) + 4 * g + ((r & 1) << 1);
    uint_t lo = __half_as_ushort(__float2half_rn(W2[node * HH + j0]));
    uint_t hi = __half_as_ushort(__float2half_rn(W2[node * HH + j0 + 1]));
    epi4[idx] = lo | (hi << 16);
  } else if (idx < NN * 16 + NN) {
    int node = idx - NN * 16;
    b2t[node] = b2[node];
  }
}

// ======================= main =======================
__global__ __launch_bounds__(TPB, 4) void dag_mfma_em(
    const ushort_t* __restrict__ xTh,  // [N][B] fp16
    const int* __restrict__ order,     // [D][N]
    const int* __restrict__ do_idx_p,  // [1]
    const ushort_t* __restrict__ W1M,  // [D][N][4096] fp16 swizzled
    const uint_t* __restrict__ epi4_g, // [N][16]
    const float* __restrict__ b2t_g,   // [N]
    float* __restrict__ out)           // [D][B][N]
{
  __shared__ __align__(16) char smem[SMEM_BYTES];
  const char* sp = (const char*)smem;

  const int d = blockIdx.y;
  const int bx = blockIdx.x;
  const int tid = threadIdx.x;
  const int w = tid >> 6;        // 16 waves
  const int lane = tid & 63;
  const int g = lane >> 4;
  const int n16 = lane & 15;
  const int di = __builtin_amdgcn_readfirstlane(do_idx_p[0]);
  const int* ord = order + d * NN;
  const int rowbase = bx * 512 + w * 32 + n16;

  // preloads: epi4 (400 uint4), b2t (100 f32)
  {
    const uint4* s4 = (const uint4*)epi4_g;
    uint4* d4 = (uint4*)(smem + EPI4_OFF);
    for (int i = tid; i < 400; i += TPB) d4[i] = s4[i];
    if (tid < NN) ((float*)(smem + B2T_OFF))[tid] = b2t_g[tid];
  }

  const ushort_t* Wd = W1M + (size_t)d * NN * 4096;

  // per-lane swizzled within-tile byte offsets, per S
  int vs[4];
#pragma unroll
  for (int S = 0; S < 4; ++S) {
    int hw = n16 * KP + ((8 * g) ^ ((n16 & 3) << 3)) + 32 * (S ^ ((n16 >> 2) & 1));
    vs[S] = 2 * hw;
  }
  int tsb = 32768;   // toggled to 0 at first superstep top

  // nodes for superstep 0; prologue DMA into set 0
  int nd[4], nn2[4];
#pragma unroll
  for (int q = 0; q < 4; ++q) { nd[q] = __builtin_amdgcn_readfirstlane(ord[q]); nn2[q] = nd[q]; }
  {
    const int q2 = tid >> 8, sub = tid & 255;   // 256 threads per tile
    const int nsel = SELQ(nd, q2);
    const char* gb = (const char*)(Wd + (size_t)nsel * 4096);
    char* lb = (char*)smem + q2 * 8192;
    __builtin_amdgcn_global_load_lds((const AS_GLOBAL void*)(gb + sub * 16),
                                     (AS_LDS void*)(lb + sub * 16), 16, 0, 0);
    __builtin_amdgcn_global_load_lds((const AS_GLOBAL void*)(gb + 4096 + sub * 16),
                                     (AS_LDS void*)(lb + 4096 + sub * 16), 16, 0, 0);
  }
  // x for step 0 (global, fp16 bits)
  ushort_t xbc[2], xbn[2];
  {
    const ushort_t* xp = xTh + (size_t)nd[0] * BB + rowbase;
    xbc[0] = xp[0];
    xbc[1] = xp[16];
  }

  // breg[nt][S]: lane(g,n16) holds k=32S+8g+{0..7}, row rowbase+16nt
  // k=101 (S=3 .z hi, g==0) = 1.0 (b1 row); k=100 (.z lo) = per-step x
  uint4 breg[2][4];
#pragma unroll
  for (int nt = 0; nt < 2; ++nt) {
#pragma unroll
    for (int S = 0; S < 4; ++S) breg[nt][S] = make_uint4(0u, 0u, 0u, 0u);
    breg[nt][3].z = (g == 0) ? 0x3C000000u : 0u;
  }

  const f32x4 zero4 = {0.f, 0.f, 0.f, 0.f};
  PU c001; c001.u = 0x211F211Fu;   // fp16 0.01 x2

#pragma unroll 1
  for (int ss = 0; ss < 25; ++ss) {
    asm volatile("s_waitcnt vmcnt(0) lgkmcnt(0)" ::: "memory");
    __builtin_amdgcn_s_barrier();
    __builtin_amdgcn_sched_barrier(0);

    tsb ^= 32768;

    if (ss < 24) {
#pragma unroll
      for (int q = 0; q < 4; ++q)
        nn2[q] = __builtin_amdgcn_readfirstlane(ord[4 * (ss + 1) + q]);
      const int dset = tsb ^ 32768;
      const int q2 = tid >> 8, sub = tid & 255;
      const int nsel = SELQ(nn2, q2);
      const char* gb = (const char*)(Wd + (size_t)nsel * 4096);
      char* lb = (char*)smem + dset + q2 * 8192;
      __builtin_amdgcn_global_load_lds((const AS_GLOBAL void*)(gb + sub * 16),
                                       (AS_LDS void*)(lb + sub * 16), 16, 0, 0);
      __builtin_amdgcn_global_load_lds((const AS_GLOBAL void*)(gb + 4096 + sub * 16),
                                       (AS_LDS void*)(lb + 4096 + sub * 16), 16, 0, 0);
    }

    // ---- 4 steps, barrier-free
#pragma unroll
    for (int q = 0; q < 4; ++q) {
      const int node = nd[q];

      // prefetch next step's x
      {
        const int node_nx = (q < 3) ? nd[q + 1] : nn2[0];
        const ushort_t* xp = xTh + (size_t)node_nx * BB + rowbase;
        xbn[0] = xp[0];
        xbn[1] = xp[16];
      }

      // insert x at k=100 (S=3 .z lo, owner g==0); hi half is 1.0
#pragma unroll
      for (int nt = 0; nt < 2; ++nt) {
        uint_t ins = 0x3C000000u | (uint_t)xbc[nt];
        breg[nt][3].z = (g == 0) ? ins : breg[nt][3].z;
      }

      // insert coordinates for k=node (wave-uniform)
      const int sn = node >> 5;
      const int en2 = (node >> 1) & 3;
      const int gn = (node >> 3) & 3;
      const int hin = node & 1;
      const bool own = (g == gn);

      ushort_t hv[2];
      if (node != di) {
        const uint4 w4 = *(const uint4*)(sp + EPI4_OFF + node * 64 + g * 16);
        const float b2n = *(const float*)(sp + B2T_OFF + node * 4);
        const int tb = tsb + q * 8192;

        f32x4 acc0[2], acc1[2];

        __builtin_amdgcn_s_setprio(1);
#pragma unroll
        for (int S = 0; S < 4; ++S) {
          FU a0, a1;
          a0.u = *(const uint4*)(sp + tb + vs[S]);
          a1.u = *(const uint4*)(sp + tb + 4096 + vs[S]);
#pragma unroll
          for (int nt = 0; nt < 2; ++nt) {
            FU bu; bu.u = breg[nt][S];
            if (S == 0) {
              acc0[nt] = __builtin_amdgcn_mfma_f32_16x16x32_f16(a0.h, bu.h, zero4, 0, 0, 0);
              acc1[nt] = __builtin_amdgcn_mfma_f32_16x16x32_f16(a1.h, bu.h, zero4, 0, 0, 0);
            } else {
              acc0[nt] = __builtin_amdgcn_mfma_f32_16x16x32_f16(a0.h, bu.h, acc0[nt], 0, 0, 0);
              acc1[nt] = __builtin_amdgcn_mfma_f32_16x16x32_f16(a1.h, bu.h, acc1[nt], 0, 0, 0);
            }
          }
        }
        __builtin_amdgcn_s_setprio(0);

        // epilogue MFMA: A = W2 (B-frag order) on single row i0=4*gn; C = b2 splat
        const int i0 = 4 * gn;
        const bool arow = (n16 == i0);
        uint4 aepi;
        aepi.x = arow ? w4.x : 0u;
        aepi.y = arow ? w4.y : 0u;
        aepi.z = arow ? w4.z : 0u;
        aepi.w = arow ? w4.w : 0u;
        const f32x4 cb2 = {b2n, b2n, b2n, b2n};

#pragma unroll
        for (int nt = 0; nt < 2; ++nt) {
          PU h01, h23, h45, h67;
          h01.p = __builtin_amdgcn_cvt_pkrtz(acc0[nt][0], acc0[nt][1]);
          h23.p = __builtin_amdgcn_cvt_pkrtz(acc0[nt][2], acc0[nt][3]);
          h45.p = __builtin_amdgcn_cvt_pkrtz(acc1[nt][0], acc1[nt][1]);
          h67.p = __builtin_amdgcn_cvt_pkrtz(acc1[nt][2], acc1[nt][3]);
          h01.p = __builtin_elementwise_max(h01.p, h01.p * c001.p);
          h23.p = __builtin_elementwise_max(h23.p, h23.p * c001.p);
          h45.p = __builtin_elementwise_max(h45.p, h45.p * c001.p);
          h67.p = __builtin_elementwise_max(h67.p, h67.p * c001.p);
          FU bm;
          bm.u = make_uint4(h01.u, h23.u, h45.u, h67.u);
          f32x4 dv = __builtin_amdgcn_mfma_f32_16x16x32_f16(
              ((FU*)&aepi)->h, bm.h, cb2, 0, 0, 0);
          // val (dot + b2) lands in dv[0] on lanes g==gn, col = n16
          hv[nt] = __half_as_ushort(__float2half_rn(dv[0]));
        }
      } else {
        hv[0] = xbc[0];
        hv[1] = xbc[1];
      }

      // insert hv at k=node: wave-uniform selects
#pragma unroll
      for (int S = 0; S < 4; ++S) {
        if (S != sn) continue;    // uniform
#pragma unroll
        for (int nt = 0; nt < 2; ++nt) {
          uint4& Bq = breg[nt][S];
          uint_t hvn = (uint_t)hv[nt];
          if (en2 == 0) {
            uint_t old = Bq.x;
            uint_t nw = hin ? ((old & 0x0000FFFFu) | (hvn << 16)) : ((old & 0xFFFF0000u) | hvn);
            Bq.x = own ? nw : old;
          } else if (en2 == 1) {
            uint_t old = Bq.y;
            uint_t nw = hin ? ((old & 0x0000FFFFu) | (hvn << 16)) : ((old & 0xFFFF0000u) | hvn);
            Bq.y = own ? nw : old;
          } else if (en2 == 2) {
            uint_t old = Bq.z;
            uint_t nw = hin ? ((old & 0x0000FFFFu) | (hvn << 16)) : ((old & 0xFFFF0000u) | hvn);
            Bq.z = own ? nw : old;
          } else {
            uint_t old = Bq.w;
            uint_t nw = hin ? ((old & 0x0000FFFFu) | (hvn << 16)) : ((old & 0xFFFF0000u) | hvn);
            Bq.w = own ? nw : old;
          }
        }
      }

      xbc[0] = xbn[0];
      xbc[1] = xbn[1];
    }

#pragma unroll
    for (int q = 0; q < 4; ++q) nd[q] = nn2[q];
  }

  // ---- output: per-wave 32-row LDS transpose chunks
  ushort_t* tbuf = (ushort_t*)smem;   // 32*132 halfs = 8448B (stage area reuse)
#pragma unroll 1
  for (int c = 0; c < 16; ++c) {
    __syncthreads();
    if (w == c) {
#pragma unroll
      for (int nt = 0; nt < 2; ++nt) {
        int r = nt * 16 + n16;
#pragma unroll
        for (int S = 0; S < 4; ++S) {
          int k = 32 * S + 8 * g;
          *(uint2*)&tbuf[r * 132 + k] = make_uint2(breg[nt][S].x, breg[nt][S].y);
          *(uint2*)&tbuf[r * 132 + k + 4] = make_uint2(breg[nt][S].z, breg[nt][S].w);
        }
      }
    }
    __syncthreads();
    const size_t obase = ((size_t)d * BB + bx * 512 + c * 32) * NN;
    for (int idx = tid; idx < 32 * NN; idx += TPB) {
      int rl = idx / NN;
      int col = idx - rl * NN;
      out[obase + idx] = __half2float(__ushort_as_half(tbuf[rl * 132 + col]));
    }
  }
}

// ======================= launch =======================
extern "C" void kernel_launch(void* const* d_in, const int* in_sizes, int n_in,
                              void* d_out, int out_size, void* d_ws, size_t ws_size,
                              hipStream_t stream) {
  const float* x     = (const float*)d_in[0];
  const float* A     = (const float*)d_in[1];
  const int* order   = (const int*)d_in[2];
  const int* do_idx  = (const int*)d_in[3];
  const float* W1    = (const float*)d_in[4];
  const float* b1    = (const float*)d_in[5];
  const float* W2    = (const float*)d_in[6];
  const float* b2    = (const float*)d_in[7];
  float* out = (float*)d_out;

  char* ws = (char*)d_ws;
  const size_t XTH_B = (size_t)BB * NN * 2;         // 1,638,400
  const size_t W1M_B = (size_t)DD * NN * 4096 * 2;  // 26,214,400
  ushort_t* xTh = (ushort_t*)ws;
  ushort_t* W1M = (ushort_t*)(ws + XTH_B);
  uint_t* epi4  = (uint_t*)(ws + XTH_B + W1M_B);            // 6,400 B
  float* b2t    = (float*)(ws + XTH_B + W1M_B + 6400);      // 400 B

  hipLaunchKernelGGL(prep_xth, dim3((BB * NN) / 256), dim3(256), 0, stream, x, xTh);
  hipLaunchKernelGGL(prep_w1m, dim3((DD * NN * 4096) / 256), dim3(256), 0, stream,
                     A, W1, b1, W1M);
  hipLaunchKernelGGL(prep_epi4, dim3((NN * 16 + NN + 255) / 256), dim3(256), 0, stream,
                     W2, b2, epi4, b2t);
  hipLaunchKernelGGL(dag_mfma_em, dim3(BB / 512, DD), dim3(TPB), 0, stream,
                     xTh, order, do_idx, W1M, epi4, b2t, out);
}

// Round 18
// 265.423 us; speedup vs baseline: 2.7034x; 1.0743x over previous
//
#include <hip/hip_runtime.h>
#include <hip/hip_fp16.h>

#define NN 100   // nodes
#define HH 32    // hidden
#define BB 8192  // batch
#define DD 32    // dags
#define KP 128   // padded K
#define TPB 1024 // 16 waves per block, 32 rows per wave

typedef _Float16 f16x8 __attribute__((ext_vector_type(8)));
typedef _Float16 f16x2 __attribute__((ext_vector_type(2)));
typedef __fp16 fph2 __attribute__((ext_vector_type(2)));
typedef float f32x4 __attribute__((ext_vector_type(4)));
typedef unsigned short ushort_t;
typedef unsigned int uint_t;
union FU { uint4 u; f16x8 h; };
union PU { fph2 p; f16x2 h; uint_t u; };

#define AS_GLOBAL __attribute__((address_space(1)))
#define AS_LDS    __attribute__((address_space(3)))

// ======================= prep =======================
// x (B,N) f32 -> xTh (N,B) fp16
__global__ void prep_xth(const float* __restrict__ x, ushort_t* __restrict__ xTh) {
  int idx = blockIdx.x * 256 + threadIdx.x;
  if (idx >= BB * NN) return;
  int b = idx & (BB - 1);
  int n = idx >> 13;
  xTh[idx] = __half_as_ushort(__float2half_rn(x[(size_t)b * NN + n]));
}

// W1M[d][node]: 32x128 fp16 tile, swizzled (j*128+k)^((j&7)<<3)
// k<100: mask*W1; k==100: x-weight; k==101: b1; else 0
__global__ void prep_w1m(const float* __restrict__ A, const float* __restrict__ W1,
                         const float* __restrict__ b1, ushort_t* __restrict__ W1M) {
  int idx = blockIdx.x * 256 + threadIdx.x;   // DD*NN*4096
  int tile = idx >> 12;
  int d = tile / NN;
  int node = tile - d * NN;
  int rem = idx & 4095;
  int j = rem >> 7;
  int k = rem & 127;
  float v = 0.f;
  if (k < NN) {
    float m = A[((size_t)d * NN + k) * NN + node];
    v = (m != 0.f) ? W1[((size_t)node * HH + j) * (NN + 1) + k] : 0.f;
  } else if (k == NN) {
    v = W1[((size_t)node * HH + j) * (NN + 1) + NN];
  } else if (k == NN + 1) {
    v = b1[node * HH + j];
  }
  int t = (j * KP + k) ^ ((j & 7) << 3);
  W1M[(size_t)tile * 4096 + t] = __half_as_ushort(__float2half_rn(v));
}

// epi3[node][20] uints: 0..15 = half2(W2[2c],W2[2c+1]); 16 = b2 bits; 17..19 pad
__global__ void prep_epi3(const float* __restrict__ W2, const float* __restrict__ b2,
                          uint_t* __restrict__ epi) {
  int idx = blockIdx.x * 256 + threadIdx.x;
  if (idx >= NN * 20) return;
  int node = idx / 20;
  int c = idx - node * 20;
  uint_t v = 0u;
  if (c < 16) {
    uint_t lo = __half_as_ushort(__float2half_rn(W2[node * HH + 2 * c]));
    uint_t hi = __half_as_ushort(__float2half_rn(W2[node * HH + 2 * c + 1]));
    v = lo | (hi << 16);
  } else if (c == 16) {
    v = __float_as_uint(b2[node]);
  }
  epi[idx] = v;
}

// ======================= main =======================
// LDS: tiles 2 sets x 4 x 8192B = 65536 @0; xstage 2 sets x 4096B @65536;
// epi 8000B @73728; total 81728 (2 blocks/CU -> 32 waves/CU = HW max)
#define XS_OFF 65536
#define EPI_OFF 73728
#define SMEM_BYTES (73728 + 8000)

__global__ __launch_bounds__(TPB, 8) void dag_mfma_ss(
    const ushort_t* __restrict__ xTh,  // [N][B] fp16
    const int* __restrict__ order,     // [D][N]
    const int* __restrict__ do_idx_p,  // [1]
    const ushort_t* __restrict__ W1M,  // [D][N][4096] fp16 swizzled
    const uint_t* __restrict__ epi_g,  // [N][20]
    float* __restrict__ out)           // [D][B][N]
{
  __shared__ __align__(16) char smem[SMEM_BYTES];
  ushort_t* stage = (ushort_t*)smem;
  const char* sp = (const char*)smem;
  uint_t* epi_l = (uint_t*)(smem + EPI_OFF);

  const int d = blockIdx.y;
  const int bx = blockIdx.x;
  const int tid = threadIdx.x;
  const int w = tid >> 6;        // 16 waves
  const int lane = tid & 63;
  const int g = lane >> 4;
  const int n16 = lane & 15;
  const int di = __builtin_amdgcn_readfirstlane(do_idx_p[0]);

  // epi preload (500 uint4)
  {
    const uint4* s4 = (const uint4*)epi_g;
    uint4* d4 = (uint4*)epi_l;
    for (int i = tid; i < 500; i += TPB) d4[i] = s4[i];
  }

  const ushort_t* Wd = W1M + (size_t)d * NN * 4096;
  const int* ord = order + d * NN;

  // per-lane swizzled ds_read byte offsets (within a tile), per S
  int vs[4];
#pragma unroll
  for (int S = 0; S < 4; ++S) {
    int hw = n16 * 128 + ((8 * g) ^ ((n16 & 3) << 3)) + 32 * (S ^ ((n16 >> 2) & 1));
    vs[S] = 2 * hw + 32768;   // +32768: loop-top XOR flips to set0 first
  }
  // x-stage byte base for this thread's wave rows (set-toggled alongside vs)
  int xso = XS_OFF + (w * 32 + n16) * 2 + 4096;   // + q*1024 + nt*32 at use

  // nodes + stage for superstep 0 (tiles: waves 0-7; x: waves 0-3)
  int nd[4], nn[4];
#pragma unroll
  for (int q = 0; q < 4; ++q) nd[q] = __builtin_amdgcn_readfirstlane(ord[q]);
  if (w < 8) {
#pragma unroll
    for (int q = 0; q < 4; ++q) {
      const ushort_t* gsrc = Wd + (size_t)nd[q] * 4096 + tid * 8;
      __builtin_amdgcn_global_load_lds((const AS_GLOBAL void*)gsrc,
          (AS_LDS void*)(stage + q * 4096 + (w << 9)), 16, 0, 0);
    }
  }
#pragma unroll
  for (int q = 0; q < 4; ++q) {
    if (w == q) {   // wave-uniform; 64 lanes x 16B = 1KB column
      const ushort_t* gx = xTh + (size_t)nd[q] * BB + bx * 512 + lane * 8;
      __builtin_amdgcn_global_load_lds((const AS_GLOBAL void*)gx,
          (AS_LDS void*)(smem + XS_OFF + q * 1024), 16, 0, 0);
    }
  }

  // B-operand: breg[nt][S]: lane(g,n16) holds k=32S+8g+{0..7}, row = block
  // rows [bx*512 + w*32 + nt*16 + n16]; k=101 (S=3 .z hi, g==0) = 1.0 (b1 row)
  uint4 breg[2][4];
#pragma unroll
  for (int nt = 0; nt < 2; ++nt) {
#pragma unroll
    for (int S = 0; S < 4; ++S) breg[nt][S] = make_uint4(0u, 0u, 0u, 0u);
    breg[nt][3].z = (g == 0) ? 0x3C000000u : 0u;
  }

  const f32x4 zero4 = {0.f, 0.f, 0.f, 0.f};
  PU c001; c001.u = 0x211F211Fu;   // fp16 0.01 x2

#pragma unroll 1
  for (int ss = 0; ss < 25; ++ss) {
    // superstep top: everything outstanding is exactly what we need
    asm volatile("s_waitcnt vmcnt(0) lgkmcnt(0)" ::: "memory");
    __builtin_amdgcn_s_barrier();
    __builtin_amdgcn_sched_barrier(0);

#pragma unroll
    for (int S = 0; S < 4; ++S) vs[S] ^= 32768;   // toggle tile set
    xso ^= 4096;                                   // toggle x set

    const bool more = (ss < 24);
    if (more) {
      // issue next superstep's tiles + x columns into the other set
#pragma unroll
      for (int q = 0; q < 4; ++q)
        nn[q] = __builtin_amdgcn_readfirstlane(ord[4 * (ss + 1) + q]);
      const int dsts = (((ss + 1) & 1) << 14);   // halfword offset of tile set
      if (w < 8) {
#pragma unroll
        for (int q = 0; q < 4; ++q) {
          const ushort_t* gsrc = Wd + (size_t)nn[q] * 4096 + tid * 8;
          __builtin_amdgcn_global_load_lds((const AS_GLOBAL void*)gsrc,
              (AS_LDS void*)(stage + dsts + q * 4096 + (w << 9)), 16, 0, 0);
        }
      }
      const int xdst = XS_OFF + (((ss + 1) & 1) << 12);
#pragma unroll
      for (int q = 0; q < 4; ++q) {
        if (w == q) {
          const ushort_t* gx = xTh + (size_t)nn[q] * BB + bx * 512 + lane * 8;
          __builtin_amdgcn_global_load_lds((const AS_GLOBAL void*)gx,
              (AS_LDS void*)(smem + xdst + q * 1024), 16, 0, 0);
        }
      }
    }

    // ---- 4 steps, barrier-free
#pragma unroll
    for (int q = 0; q < 4; ++q) {
      const int node = nd[q];

      // x bits for this step's 2 row-tiles (fp16, from LDS)
      ushort_t xb[2];
#pragma unroll
      for (int nt = 0; nt < 2; ++nt)
        xb[nt] = *(const ushort_t*)(sp + xso + q * 1024 + nt * 32);

      // insert x at k=100 (S=3 .z lo, owner g==0); hi half is always 1.0
#pragma unroll
      for (int nt = 0; nt < 2; ++nt) {
        uint_t ins = 0x3C000000u | (uint_t)xb[nt];
        breg[nt][3].z = (g == 0) ? ins : breg[nt][3].z;
      }

      float val[2];
      if (node != di) {
        const char* ep = (const char*)epi_l + node * 80;
        const float b2n = *(const float*)(ep + 64);

        f32x4 acc[2];
        float p0[2];

        // ---- phase 0: j = 4g + r4 (tile row n16)
        {
          __builtin_amdgcn_s_setprio(1);
#pragma unroll
          for (int S = 0; S < 4; ++S) {
            FU a0;
            a0.u = *(const uint4*)(sp + vs[S] + q * 8192);
#pragma unroll
            for (int nt = 0; nt < 2; ++nt) {
              FU bu; bu.u = breg[nt][S];
              if (S == 0)
                acc[nt] = __builtin_amdgcn_mfma_f32_16x16x32_f16(a0.h, bu.h, zero4, 0, 0, 0);
              else
                acc[nt] = __builtin_amdgcn_mfma_f32_16x16x32_f16(a0.h, bu.h, acc[nt], 0, 0, 0);
            }
          }
          __builtin_amdgcn_s_setprio(0);
          const uint2 wlo = *(const uint2*)(ep + 8 * g);   // j=4g..4g+3 as half2 x2
          PU w01, w23; w01.u = wlo.x; w23.u = wlo.y;
#pragma unroll
          for (int nt = 0; nt < 2; ++nt) {
            PU h01, h23;
            h01.p = __builtin_amdgcn_cvt_pkrtz(acc[nt][0], acc[nt][1]);
            h23.p = __builtin_amdgcn_cvt_pkrtz(acc[nt][2], acc[nt][3]);
            h01.p = __builtin_elementwise_max(h01.p, h01.p * c001.p);
            h23.p = __builtin_elementwise_max(h23.p, h23.p * c001.p);
            float p = __builtin_amdgcn_fdot2(h01.h, w01.h, 0.f, false);
            p0[nt] = __builtin_amdgcn_fdot2(h23.h, w23.h, p, false);
          }
        }

        // ---- phase 1: j = 16 + 4g + r4 (tile row 16+n16), reuse acc regs
        {
          __builtin_amdgcn_s_setprio(1);
#pragma unroll
          for (int S = 0; S < 4; ++S) {
            FU a1;
            a1.u = *(const uint4*)(sp + vs[S] + q * 8192 + 4096);
#pragma unroll
            for (int nt = 0; nt < 2; ++nt) {
              FU bu; bu.u = breg[nt][S];
              if (S == 0)
                acc[nt] = __builtin_amdgcn_mfma_f32_16x16x32_f16(a1.h, bu.h, zero4, 0, 0, 0);
              else
                acc[nt] = __builtin_amdgcn_mfma_f32_16x16x32_f16(a1.h, bu.h, acc[nt], 0, 0, 0);
            }
          }
          __builtin_amdgcn_s_setprio(0);
          const uint2 whi = *(const uint2*)(ep + 32 + 8 * g);  // j=16+4g..
          PU w45, w67; w45.u = whi.x; w67.u = whi.y;
#pragma unroll
          for (int nt = 0; nt < 2; ++nt) {
            PU h45, h67;
            h45.p = __builtin_amdgcn_cvt_pkrtz(acc[nt][0], acc[nt][1]);
            h67.p = __builtin_amdgcn_cvt_pkrtz(acc[nt][2], acc[nt][3]);
            h45.p = __builtin_elementwise_max(h45.p, h45.p * c001.p);
            h67.p = __builtin_elementwise_max(h67.p, h67.p * c001.p);
            float p = __builtin_amdgcn_fdot2(h45.h, w45.h, p0[nt], false);
            p = __builtin_amdgcn_fdot2(h67.h, w67.h, p, false);
            p += __shfl_xor(p, 16, 64);
            p += __shfl_xor(p, 32, 64);
            val[nt] = p + b2n;
          }
        }
      } else {
#pragma unroll
        for (int nt = 0; nt < 2; ++nt)
          val[nt] = __half2float(__ushort_as_half(xb[nt]));
      }

      // insert val (fp16) at k=node: wave-uniform selects
      const int sn = node >> 5;
      const int en2 = (node >> 1) & 3;
      const int gn = (node >> 3) & 3;
      const int hin = node & 1;
      const bool own = (g == gn);
      ushort_t hv[2];
#pragma unroll
      for (int nt = 0; nt < 2; ++nt) hv[nt] = __half_as_ushort(__float2half_rn(val[nt]));
#pragma unroll
      for (int S = 0; S < 4; ++S) {
        if (S != sn) continue;    // uniform
#pragma unroll
        for (int nt = 0; nt < 2; ++nt) {
          uint4& Bq = breg[nt][S];
          uint_t hvn = (uint_t)hv[nt];
          if (en2 == 0) {
            uint_t old = Bq.x;
            uint_t nw = hin ? ((old & 0x0000FFFFu) | (hvn << 16)) : ((old & 0xFFFF0000u) | hvn);
            Bq.x = own ? nw : old;
          } else if (en2 == 1) {
            uint_t old = Bq.y;
            uint_t nw = hin ? ((old & 0x0000FFFFu) | (hvn << 16)) : ((old & 0xFFFF0000u) | hvn);
            Bq.y = own ? nw : old;
          } else if (en2 == 2) {
            uint_t old = Bq.z;
            uint_t nw = hin ? ((old & 0x0000FFFFu) | (hvn << 16)) : ((old & 0xFFFF0000u) | hvn);
            Bq.z = own ? nw : old;
          } else {
            uint_t old = Bq.w;
            uint_t nw = hin ? ((old & 0x0000FFFFu) | (hvn << 16)) : ((old & 0xFFFF0000u) | hvn);
            Bq.w = own ? nw : old;
          }
        }
      }
    }

#pragma unroll
    for (int q = 0; q < 4; ++q) nd[q] = nn[q];
  }

  // ---- output: per-wave 32-row LDS transpose chunks (tbuf @ smem base)
  ushort_t* tbuf = (ushort_t*)smem;   // 32*132 halfs = 8448B
#pragma unroll 1
  for (int c = 0; c < 16; ++c) {
    __syncthreads();
    if (w == c) {
#pragma unroll
      for (int nt = 0; nt < 2; ++nt) {
        int r = nt * 16 + n16;
#pragma unroll
        for (int S = 0; S < 4; ++S) {
          int k = 32 * S + 8 * g;
          *(uint2*)&tbuf[r * 132 + k] = make_uint2(breg[nt][S].x, breg[nt][S].y);
          *(uint2*)&tbuf[r * 132 + k + 4] = make_uint2(breg[nt][S].z, breg[nt][S].w);
        }
      }
    }
    __syncthreads();
    const size_t obase = ((size_t)d * BB + bx * 512 + c * 32) * NN;
    for (int idx = tid; idx < 32 * NN; idx += TPB) {
      int rl = idx / NN;
      int col = idx - rl * NN;
      out[obase + idx] = __half2float(__ushort_as_half(tbuf[rl * 132 + col]));
    }
  }
}

// ======================= launch =======================
extern "C" void kernel_launch(void* const* d_in, const int* in_sizes, int n_in,
                              void* d_out, int out_size, void* d_ws, size_t ws_size,
                              hipStream_t stream) {
  const float* x     = (const float*)d_in[0];
  const float* A     = (const float*)d_in[1];
  const int* order   = (const int*)d_in[2];
  const int* do_idx  = (const int*)d_in[3];
  const float* W1    = (const float*)d_in[4];
  const float* b1    = (const float*)d_in[5];
  const float* W2    = (const float*)d_in[6];
  const float* b2    = (const float*)d_in[7];
  float* out = (float*)d_out;

  char* ws = (char*)d_ws;
  const size_t XTH_B = (size_t)BB * NN * 2;         // 1,638,400
  const size_t W1M_B = (size_t)DD * NN * 4096 * 2;  // 26,214,400
  ushort_t* xTh = (ushort_t*)ws;
  ushort_t* W1M = (ushort_t*)(ws + XTH_B);
  uint_t* epi   = (uint_t*)(ws + XTH_B + W1M_B);    // 8,000 B

  hipLaunchKernelGGL(prep_xth, dim3((BB * NN) / 256), dim3(256), 0, stream, x, xTh);
  hipLaunchKernelGGL(prep_w1m, dim3((DD * NN * 4096) / 256), dim3(256), 0, stream,
                     A, W1, b1, W1M);
  hipLaunchKernelGGL(prep_epi3, dim3((NN * 20 + 255) / 256), dim3(256), 0, stream,
                     W2, b2, epi);
  hipLaunchKernelGGL(dag_mfma_ss, dim3(BB / 512, DD), dim3(TPB), 0, stream,
                     xTh, order, do_idx, W1M, epi, out);
}